// Round 8
// baseline (187.470 us; speedup 1.0000x reference)
//
#include <hip/hip_runtime.h>

#define DIM   128
#define HALF  64          // columns per slice (2 slices, XCD-parity L2 residency)
#define CPT   256         // chars per wave-chunk
#define TAIL  64          // lookahead window for cross-chunk tails
#define WPB   4           // waves per block
#define BAT   8           // chars per batch (32 batches/chunk), 4 rotating buffers
#define NB    (CPT / BAT)

// out = N - <H,T>_F / (||H||_F ||T||_F).  T never materialized.
// Wave layout: lane = column of a 64-col slice; all control is wave-uniform.
// All per-char ids/flush tests run on the SCALAR pipe: start is forced
// uniform (readfirstlane) so char_ids/seg_ids reads become s_load into SGPRs
// and the boundary test is s_cmp+s_cbranch. VALU per char ~= 1 acc add +
// 1 addr op; VMEM = 1 dword load from the L2-resident char slice.
__global__ __launch_bounds__(256) void fused_kernel(
    const float* __restrict__ char_emb,
    const float* __restrict__ ent,
    const int* __restrict__ head_ids,
    const int* __restrict__ char_ids,
    const int* __restrict__ seg_ids,
    float* __restrict__ pb,        // [gridDim.x*3] block partials: ht,tt,hh
    int total_chars, int n_triples, int hh_per_block)
{
    __shared__ float r_scr[3][WPB];
    const int tid  = threadIdx.x;
    const int lane = tid & 63;
    const int wid  = tid >> 6;

    float ht = 0.f, tt = 0.f, hh = 0.f;

    const int slice = blockIdx.x & 1;         // XCD-parity slice mapping
    const int chunk = (blockIdx.x >> 1) * WPB + wid;
    const int start = __builtin_amdgcn_readfirstlane(chunk * CPT);
    const int len   = min(CPT, total_chars - start);
    const int sl    = min(CPT + TAIL, total_chars - start);

    // uniform bases pre-offset to this slice's 64 columns
    const float* __restrict__ cbase =
        (const float*)((const char*)char_emb + (slice << 8));
    const float* __restrict__ ebase =
        (const float*)((const char*)ent + (slice << 8));

    if (len == CPT) {
        // -------- fast path: whole chunk staged on the scalar pipe --------
        int cur   = seg_ids[start];                       // uniform -> s_load
        bool live = (start == 0) || (seg_ids[start - 1] != cur);
        float hv  = ebase[(size_t)((unsigned)head_ids[cur] * DIM) + lane];
        float acc = 0.f;

        int   cb_[4][BAT];     // char ids   (SGPRs)
        int   sb_[4][BAT];     // seg ids    (SGPRs)
        float vb_[4][BAT];     // gathered values (VGPRs)

#define LOADI(BUF, B) { _Pragma("unroll") \
    for (int j = 0; j < BAT; ++j) { \
        cb_[BUF][j] = char_ids[start + (B) * BAT + j]; \
        sb_[BUF][j] = seg_ids[start + (B) * BAT + j]; } }

#define LOADV(BUF) { _Pragma("unroll") \
    for (int j = 0; j < BAT; ++j) { \
        vb_[BUF][j] = cbase[((unsigned)cb_[BUF][j] << 7) + lane]; } }

#define CONS(BUF) { _Pragma("unroll") \
    for (int j = 0; j < BAT; ++j) { \
        if (sb_[BUF][j] != cur) {              /* scalar cmp + branch */ \
            if (live) { ht = fmaf(hv, acc, ht); tt = fmaf(acc, acc, tt); } \
            live = true; acc = 0.f; cur = sb_[BUF][j]; \
            hv = ebase[(size_t)((unsigned)head_ids[cur] * DIM) + lane]; } \
        acc += vb_[BUF][j]; } }

        LOADI(0, 0) LOADI(1, 1)
        LOADV(0)    LOADV(1)
#pragma unroll
        for (int b = 0; b < NB; ++b) {
            if (b + 2 < NB) LOADI((b + 2) & 3, b + 2)   // ids 2 batches ahead
            CONS(b & 3)
            if (b + 2 < NB) LOADV((b + 2) & 3)          // values 2 consumes ahead
        }
#undef LOADI
#undef LOADV
#undef CONS

        if (live) {
            // tail: last owned segment may continue past chunk end
            int e = CPT;
            bool ended = false;
            while (e < sl) {
                const int idx = e + lane;
                const bool differ = (idx < sl) && (seg_ids[start + idx] != cur);
                const unsigned long long bm = __ballot(differ);
                const int run = bm ? (__ffsll((long long)bm) - 1)
                                   : min(64, sl - e);
                for (int j = 0; j < run; j += 4) {
                    const int mm = min(4, run - j);
                    float vv[4];
#pragma unroll
                    for (int q = 0; q < 4; ++q) {
                        if (q < mm) {
                            const int cid = char_ids[start + e + j + q]; // uniform
                            vv[q] = cbase[((unsigned)cid << 7) + lane];
                        }
                    }
                    for (int q = 0; q < mm; ++q) acc += vv[q];
                }
                e += run;
                if (bm) { ended = true; break; }
            }
            if (!ended && start + sl < total_chars) {
                int gg = start + sl;                 // very rare long run
                while (gg < total_chars && seg_ids[gg] == cur) {
                    acc += cbase[((unsigned)char_ids[gg] << 7) + lane];
                    ++gg;
                }
            }
            // final flush
            ht = fmaf(hv, acc, ht);
            tt = fmaf(acc, acc, tt);
        }
    } else if (len > 0) {
        // -------- rare fallback (partial last chunk): scalar per char --------
        int p = 0;
        if (start > 0) {
            const int prev = seg_ids[start - 1];
            while (p < len && seg_ids[start + p] == prev) ++p;
        }
        if (p < len) {
            int cur = seg_ids[start + p];
            float acc = 0.f;
            float hv = ebase[(size_t)((unsigned)head_ids[cur] * DIM) + lane];
            for (int c = p; c < len; ++c) {
                const int sid = seg_ids[start + c];
                if (sid != cur) {
                    ht += hv * acc; tt += acc * acc;
                    acc = 0.f; cur = sid;
                    hv = ebase[(size_t)((unsigned)head_ids[cur] * DIM) + lane];
                }
                acc += cbase[((unsigned)char_ids[start + c] << 7) + lane];
            }
            int gg = start + len;
            while (gg < total_chars && seg_ids[gg] == cur) {
                acc += cbase[((unsigned)char_ids[gg] << 7) + lane];
                ++gg;
            }
            ht += hv * acc; tt += acc * acc;
        }
    }

    // -------- hh strip for this block (covers empty segments exactly) --------
    {
        const float4* e4 = (const float4*)ent;
        const long base = (long)blockIdx.x * hh_per_block * 32;
        const long lim  = (long)n_triples * 32;
        for (int s = tid; s < hh_per_block * 32; s += 256) {
            const long f = base + s;
            if (f < lim) {
                const int row = (int)(f >> 5);
                const int hid = head_ids[row];
                const float4 v = e4[(size_t)hid * 32 + (int)(f & 31)];
                hh += v.x * v.x + v.y * v.y + v.z * v.z + v.w * v.w;
            }
        }
    }

    // -------- block reduce -> per-block partials (no atomics, no memset) ----
#pragma unroll
    for (int off = 32; off > 0; off >>= 1) {
        ht += __shfl_down(ht, off);
        tt += __shfl_down(tt, off);
        hh += __shfl_down(hh, off);
    }
    if (lane == 0) { r_scr[0][wid] = ht; r_scr[1][wid] = tt; r_scr[2][wid] = hh; }
    __syncthreads();
    if (tid == 0) {
        float a = 0.f, b = 0.f, c = 0.f;
#pragma unroll
        for (int w = 0; w < WPB; ++w) {
            a += r_scr[0][w]; b += r_scr[1][w]; c += r_scr[2][w];
        }
        pb[blockIdx.x * 3 + 0] = a;
        pb[blockIdx.x * 3 + 1] = b;
        pb[blockIdx.x * 3 + 2] = c;
    }
}

// final reduce: sums partials in double, writes N - ht/sqrt(hh*tt)
__global__ __launch_bounds__(256) void reduce_kernel(
    const float* __restrict__ pb, int nb, float* __restrict__ out,
    int n_triples)
{
    double ht = 0.0, tt = 0.0, hh = 0.0;
    for (int i = threadIdx.x; i < nb; i += 256) {
        ht += (double)pb[i * 3 + 0];
        tt += (double)pb[i * 3 + 1];
        hh += (double)pb[i * 3 + 2];
    }
#pragma unroll
    for (int off = 32; off > 0; off >>= 1) {
        ht += __shfl_down(ht, off);
        tt += __shfl_down(tt, off);
        hh += __shfl_down(hh, off);
    }
    __shared__ double sd[3][4];
    const int wid = threadIdx.x >> 6;
    if ((threadIdx.x & 63) == 0) { sd[0][wid] = ht; sd[1][wid] = tt; sd[2][wid] = hh; }
    __syncthreads();
    if (threadIdx.x == 0) {
        double a = 0.0, b = 0.0, c = 0.0;
        for (int w = 0; w < 4; ++w) { a += sd[0][w]; b += sd[1][w]; c += sd[2][w]; }
        out[0] = (float)((double)n_triples - a / sqrt(c * b));
    }
}

extern "C" void kernel_launch(void* const* d_in, const int* in_sizes, int n_in,
                              void* d_out, int out_size, void* d_ws, size_t ws_size,
                              hipStream_t stream)
{
    const float* char_emb = (const float*)d_in[0];
    const float* ent_emb  = (const float*)d_in[1];
    const int* head_ids   = (const int*)d_in[2];
    const int* char_ids   = (const int*)d_in[3];
    const int* seg_ids    = (const int*)d_in[4];
    const int n_triples   = in_sizes[2];
    const int total_chars = in_sizes[3];

    const int n_chunks = (total_chars + CPT - 1) / CPT;
    const int bps = (n_chunks + WPB - 1) / WPB;
    const int nsb = 2 * bps;                       // x2 slices
    const int hhpb = (n_triples + nsb - 1) / nsb;

    float* pb = (float*)d_ws;                      // nsb*3 floats

    fused_kernel<<<nsb, 256, 0, stream>>>(char_emb, ent_emb, head_ids,
                                          char_ids, seg_ids, pb,
                                          total_chars, n_triples, hhpb);
    reduce_kernel<<<1, 256, 0, stream>>>(pb, nsb, (float*)d_out, n_triples);
}

// Round 9
// 184.485 us; speedup vs baseline: 1.0162x; 1.0162x over previous
//
#include <hip/hip_runtime.h>

#define DIM   128
#define HALF  64          // columns per slice (2 slices, XCD-parity L2 residency)
#define CPT   256         // chars per wave-chunk
#define TAIL  64          // staged lookahead for cross-chunk tails
#define WPB   4           // waves per block
#define NHID  (CPT + 1)

// out = N - <H,T>_F / (||H||_F ||T||_F).  T never materialized.
// Lane = column of a 64-col slice; all control is wave-uniform (SGPR ballot
// masks -> scalar bit test + s_cbranch). NEW vs R7: head ids for each flush
// are pre-gathered in flush order into s_hid at staging (ballot+mbcnt
// ordinal), so the flush needs no SMEM load of head_ids (which forced
// lgkmcnt(0) drains); hv is pipelined 2 flushes deep on vmcnt only.
__global__ __launch_bounds__(256) void fused_kernel(
    const float* __restrict__ char_emb,
    const float* __restrict__ ent,
    const int* __restrict__ head_ids,
    const int* __restrict__ char_ids,
    const int* __restrict__ seg_ids,
    float* __restrict__ pb,        // [gridDim.x*3] block partials: ht,tt,hh
    int total_chars, int n_triples, int hh_per_block)
{
    __shared__ __align__(16) int s_off[WPB][CPT + TAIL];  // (cid<<9)+sco
    __shared__ int s_sid[WPB][CPT + TAIL];
    __shared__ int s_hid[WPB][NHID];   // head ids in flush order; [nb]=final
    __shared__ float r_scr[3][WPB];

    const int tid  = threadIdx.x;
    const int lane = tid & 63;
    const int wid  = tid >> 6;
    const int colb = lane << 2;               // byte offset of lane's column

    float ht = 0.f, tt = 0.f, hh = 0.f;

    const int slice = blockIdx.x & 1;         // XCD-parity slice mapping
    const int sco   = slice << 8;             // slice*64 cols*4B
    const int chunk = (blockIdx.x >> 1) * WPB + wid;
    const int start = chunk * CPT;
    const int len   = min(CPT, total_chars - start);
    const int sl    = min(CPT + TAIL, total_chars - start);
    const char* cb  = (const char*)char_emb;
    const float* ee = ent + slice * HALF + lane;

    // ---- stage offsets + sids (wave-local region) ----
    for (int c = lane; c < sl; c += 64) {
        s_off[wid][c] = (char_ids[start + c] << 9) + sco;
        s_sid[wid][c] = seg_ids[start + c];
    }

    // ---- boundary masks (SGPRs) + flush-ordered head ids (LDS) ----
    unsigned long long mk[4] = {0ull, 0ull, 0ull, 0ull};
    int nb = 0;                               // total boundary count
    if (len == CPT) {
#pragma unroll
        for (int grp = 0; grp < 4; ++grp) {
            const int c = start + grp * 64 + lane;
            const int s1 = seg_ids[c];
            const int s0 = (c > 0) ? seg_ids[c - 1] : s1;
            const bool bnd = (c == 0) || (s1 != s0);   // c==0 only at start==0
            const unsigned long long m = __ballot(bnd);
            if (bnd) {
                const int ord = nb + __builtin_amdgcn_mbcnt_hi(
                    (unsigned)(m >> 32),
                    __builtin_amdgcn_mbcnt_lo((unsigned)m, 0));
                s_hid[wid][ord] = head_ids[s0];        // head of FINISHING seg
            }
            mk[grp] = m;
            nb += __popcll(m);
        }
        if (lane == 0)                                  // final segment's head
            s_hid[wid][nb] = head_ids[seg_ids[start + CPT - 1]];
    }
    __syncthreads();

    if (len == CPT) {
        // -------- fast path --------
        const int fin = seg_ids[start + CPT - 1];       // uniform
        float acc = 0.f;
        bool live = false;        // drop first flush (continuation prefix)
        int f = 0;
        const int h0 = s_hid[wid][0];
        const int h1 = s_hid[wid][min(1, nb)];
        int hidn     = s_hid[wid][min(2, nb)];
        float hv  = ee[(size_t)(unsigned)h0 * DIM];     // row for flush 0
        float hvn = ee[(size_t)(unsigned)h1 * DIM];     // row for flush 1
        float vA[16], vB[16];

#define PF(BUF, B) { \
    _Pragma("unroll") \
    for (int q = 0; q < 4; ++q) { \
        const int4 o4 = *(const int4*)&s_off[wid][(B) * 16 + q * 4]; \
        BUF[q * 4 + 0] = *(const float*)(cb + (size_t)(unsigned)(o4.x + colb)); \
        BUF[q * 4 + 1] = *(const float*)(cb + (size_t)(unsigned)(o4.y + colb)); \
        BUF[q * 4 + 2] = *(const float*)(cb + (size_t)(unsigned)(o4.z + colb)); \
        BUF[q * 4 + 3] = *(const float*)(cb + (size_t)(unsigned)(o4.w + colb)); \
    } }

#define CS(BUF, B) { \
    _Pragma("unroll") \
    for (int j = 0; j < 16; ++j) { \
        if (mk[(B) >> 2] & (1ull << (((B) & 3) * 16 + j))) {  /* scalar test */ \
            if (live) { ht = fmaf(hv, acc, ht); tt = fmaf(acc, acc, tt); } \
            live = true; acc = 0.f; \
            hv = hvn;                                    /* pipelined head row */ \
            hvn = ee[(size_t)(unsigned)hidn * DIM]; \
            ++f; \
            hidn = s_hid[wid][min(f + 2, nb)]; \
        } \
        acc += BUF[j]; \
    } }

        PF(vA, 0)
#pragma unroll
        for (int B = 0; B < 16; ++B) {
            if (B + 1 < 16) { if (B & 1) { PF(vA, B + 1) } else { PF(vB, B + 1) } }
            if (B & 1) { CS(vB, B) } else { CS(vA, B) }
        }
#undef PF
#undef CS

        if (live) {
            // tail: last owned segment may continue past chunk end
            int e = CPT;
            bool ended = false;
            while (e < sl) {
                const int idx = e + lane;
                const bool differ = (idx < sl) && (s_sid[wid][idx] != fin);
                const unsigned long long bm = __ballot(differ);
                const int run = bm ? (__ffsll((long long)bm) - 1)
                                   : min(64, sl - e);
                for (int j = 0; j < run; j += 4) {
                    const int mm2 = min(4, run - j);
                    float vv[4];
#pragma unroll
                    for (int k = 0; k < 4; ++k) {
                        if (k < mm2)
                            vv[k] = *(const float*)(cb +
                                (size_t)(unsigned)(s_off[wid][e + j + k] + colb));
                    }
                    for (int k = 0; k < mm2; ++k) acc += vv[k];
                }
                e += run;
                if (bm) { ended = true; break; }
            }
            if (!ended && start + sl < total_chars) {
                int gg = start + sl;                 // very rare long run
                while (gg < total_chars && seg_ids[gg] == fin) {
                    acc += *(const float*)(cb +
                        (size_t)(unsigned)((char_ids[gg] << 9) + sco + colb));
                    ++gg;
                }
            }
            // final flush: hv has cycled to row(s_hid[nb]) = final head
            ht = fmaf(hv, acc, ht);
            tt = fmaf(acc, acc, tt);
        }
    } else if (len > 0) {
        // -------- rare fallback (partial last chunk): scalar per char --------
        const float* cembF = char_emb + slice * HALF + lane;
        int p = 0;
        if (start > 0) {
            const int prev = seg_ids[start - 1];
            while (p < len && seg_ids[start + p] == prev) ++p;
        }
        if (p < len) {
            int cur = seg_ids[start + p];
            float acc = 0.f;
            float hv = ee[(size_t)(unsigned)head_ids[cur] * DIM];
            for (int c = p; c < len; ++c) {
                const int sid = seg_ids[start + c];
                if (sid != cur) {
                    ht += hv * acc; tt += acc * acc;
                    acc = 0.f; cur = sid;
                    hv = ee[(size_t)(unsigned)head_ids[cur] * DIM];
                }
                acc += cembF[(size_t)(unsigned)char_ids[start + c] * DIM];
            }
            int gg = start + len;
            while (gg < total_chars && seg_ids[gg] == cur) {
                acc += cembF[(size_t)(unsigned)char_ids[gg] * DIM];
                ++gg;
            }
            ht += hv * acc; tt += acc * acc;
        }
    }

    // -------- hh strip for this block (covers empty segments exactly) --------
    {
        const float4* e4 = (const float4*)ent;
        const long base = (long)blockIdx.x * hh_per_block * 32;
        const long lim  = (long)n_triples * 32;
        for (int s = tid; s < hh_per_block * 32; s += 256) {
            const long f2 = base + s;
            if (f2 < lim) {
                const int row = (int)(f2 >> 5);
                const int hid = head_ids[row];
                const float4 v = e4[(size_t)hid * 32 + (int)(f2 & 31)];
                hh += v.x * v.x + v.y * v.y + v.z * v.z + v.w * v.w;
            }
        }
    }

    // -------- block reduce -> per-block partials (no atomics, no memset) ----
#pragma unroll
    for (int off = 32; off > 0; off >>= 1) {
        ht += __shfl_down(ht, off);
        tt += __shfl_down(tt, off);
        hh += __shfl_down(hh, off);
    }
    if (lane == 0) { r_scr[0][wid] = ht; r_scr[1][wid] = tt; r_scr[2][wid] = hh; }
    __syncthreads();
    if (tid == 0) {
        float a = 0.f, b = 0.f, c = 0.f;
#pragma unroll
        for (int w = 0; w < WPB; ++w) {
            a += r_scr[0][w]; b += r_scr[1][w]; c += r_scr[2][w];
        }
        pb[blockIdx.x * 3 + 0] = a;
        pb[blockIdx.x * 3 + 1] = b;
        pb[blockIdx.x * 3 + 2] = c;
    }
}

// final reduce: sums partials in double, writes N - ht/sqrt(hh*tt)
__global__ __launch_bounds__(256) void reduce_kernel(
    const float* __restrict__ pb, int nb, float* __restrict__ out,
    int n_triples)
{
    double ht = 0.0, tt = 0.0, hh = 0.0;
    for (int i = threadIdx.x; i < nb; i += 256) {
        ht += (double)pb[i * 3 + 0];
        tt += (double)pb[i * 3 + 1];
        hh += (double)pb[i * 3 + 2];
    }
#pragma unroll
    for (int off = 32; off > 0; off >>= 1) {
        ht += __shfl_down(ht, off);
        tt += __shfl_down(tt, off);
        hh += __shfl_down(hh, off);
    }
    __shared__ double sd[3][4];
    const int wid = threadIdx.x >> 6;
    if ((threadIdx.x & 63) == 0) { sd[0][wid] = ht; sd[1][wid] = tt; sd[2][wid] = hh; }
    __syncthreads();
    if (threadIdx.x == 0) {
        double a = 0.0, b = 0.0, c = 0.0;
        for (int w = 0; w < 4; ++w) { a += sd[0][w]; b += sd[1][w]; c += sd[2][w]; }
        out[0] = (float)((double)n_triples - a / sqrt(c * b));
    }
}

extern "C" void kernel_launch(void* const* d_in, const int* in_sizes, int n_in,
                              void* d_out, int out_size, void* d_ws, size_t ws_size,
                              hipStream_t stream)
{
    const float* char_emb = (const float*)d_in[0];
    const float* ent_emb  = (const float*)d_in[1];
    const int* head_ids   = (const int*)d_in[2];
    const int* char_ids   = (const int*)d_in[3];
    const int* seg_ids    = (const int*)d_in[4];
    const int n_triples   = in_sizes[2];
    const int total_chars = in_sizes[3];

    const int n_chunks = (total_chars + CPT - 1) / CPT;
    const int bps = (n_chunks + WPB - 1) / WPB;
    const int nsb = 2 * bps;                       // x2 slices
    const int hhpb = (n_triples + nsb - 1) / nsb;

    float* pb = (float*)d_ws;                      // nsb*3 floats

    fused_kernel<<<nsb, 256, 0, stream>>>(char_emb, ent_emb, head_ids,
                                          char_ids, seg_ids, pb,
                                          total_chars, n_triples, hhpb);
    reduce_kernel<<<1, 256, 0, stream>>>(pb, nsb, (float*)d_out, n_triples);
}